// Round 11
// baseline (218.794 us; speedup 1.0000x reference)
//
#include <hip/hip_runtime.h>
#include <hip/hip_fp16.h>
#include <stdint.h>

#define LRELU(x) ((x) > 0.0f ? (x) : 0.01f * (x))

struct h4 { __half2 a, b; };          // 4 fp16, 8 B
struct h8 { __half2 a, b, c, d; };    // 8 fp16, 16 B

typedef _Float16 f16x8 __attribute__((ext_vector_type(8)));
typedef float    f32x4 __attribute__((ext_vector_type(4)));

#define EPB 8192                      // edges per block in sort passes
#define PARTS 16                      // pooling sub-slices per graph

// ---------------- CSR build: deterministic counting sort, no global atomics ----------------

__global__ __launch_bounds__(256) void hist1_kernel(const int* __restrict__ dst,
                                                    int* __restrict__ bhist,
                                                    int nblk, int E, int nbk) {
    __shared__ int h[512];
    int blk = blockIdx.x, t = threadIdx.x;
    for (int i = t; i < nbk; i += 256) h[i] = 0;
    __syncthreads();
    #pragma unroll
    for (int k = 0; k < EPB / 1024; ++k) {
        int i4 = blk * (EPB / 4) + k * 256 + t;
        int e = i4 * 4;
        if (e + 3 < E) {
            int4 d = ((const int4*)dst)[i4];
            atomicAdd(&h[d.x >> 8], 1);
            atomicAdd(&h[d.y >> 8], 1);
            atomicAdd(&h[d.z >> 8], 1);
            atomicAdd(&h[d.w >> 8], 1);
        } else {
            for (int j = e; j < E; ++j) atomicAdd(&h[dst[j] >> 8], 1);
        }
    }
    __syncthreads();
    for (int i = t; i < nbk; i += 256) bhist[i * nblk + blk] = h[i];
}

__global__ __launch_bounds__(256) void scanb_kernel(int* __restrict__ bhist,
                                                    int* __restrict__ btot, int nblk) {
    __shared__ int s[256];
    __shared__ int carry;
    int b = blockIdx.x, t = threadIdx.x;
    if (t == 0) carry = 0;
    __syncthreads();
    for (int c0 = 0; c0 < nblk; c0 += 256) {
        int idx = c0 + t;
        int v = (idx < nblk) ? bhist[b * nblk + idx] : 0;
        s[t] = v;
        __syncthreads();
        for (int off = 1; off < 256; off <<= 1) {
            int a = (t >= off) ? s[t - off] : 0;
            __syncthreads();
            s[t] += a;
            __syncthreads();
        }
        if (idx < nblk) bhist[b * nblk + idx] = s[t] - v + carry;
        __syncthreads();
        if (t == 255) carry += s[255];
        __syncthreads();
    }
    if (t == 0) btot[b] = carry;
}

// block 0: exclusive scan of bucket totals -> bbase
// blocks 1..6: cast W (fp32 [64][64]) into per-lane MFMA B-fragment order (fp16)
__global__ __launch_bounds__(512) void bbase_wprep_kernel(const int* __restrict__ btot,
                                                          int* __restrict__ bbase,
                                                          int nbk, int E,
                                                          const float* __restrict__ w1,
                                                          const float* __restrict__ w2,
                                                          const float* __restrict__ w3,
                                                          _Float16* __restrict__ Bf) {
    if (blockIdx.x == 0) {
        __shared__ int s[512];
        int t = threadIdx.x;
        int v = (t < nbk) ? btot[t] : 0;
        s[t] = v;
        __syncthreads();
        for (int off = 1; off < 512; off <<= 1) {
            int a = (t >= off) ? s[t - off] : 0;
            __syncthreads();
            s[t] += a;
            __syncthreads();
        }
        if (t < nbk) bbase[t] = s[t] - v;
        if (t == 0) bbase[nbk] = E;
    } else {
        int bc = blockIdx.x - 1;        // 0..5 = layer*2 + c
        int tid = threadIdx.x;
        if (tid < 256) {
            int layer = bc >> 1, c = bc & 1;
            const float* W = (layer == 0) ? w1 : ((layer == 1) ? w2 : w3);
            int t = tid >> 6, l = tid & 63;
            _Float16* dstp = Bf + ((size_t)(layer * 8 + c * 4 + t) * 64 + l) * 8;
            int n  = t * 16 + (l & 15);
            int kb = c * 32 + (l >> 4) * 8;
            #pragma unroll
            for (int i = 0; i < 8; ++i) dstp[i] = (_Float16)W[(kb + i) * 64 + n];
        }
    }
}

__global__ __launch_bounds__(256) void place_kernel(const int* __restrict__ src,
                                                    const int* __restrict__ dst,
                                                    const int* __restrict__ bbase,
                                                    const int* __restrict__ bhist,
                                                    unsigned* __restrict__ bedge,
                                                    int nblk, int E, int nbk) {
    __shared__ int cur[512];
    int blk = blockIdx.x, t = threadIdx.x;
    for (int i = t; i < nbk; i += 256) cur[i] = bbase[i] + bhist[i * nblk + blk];
    __syncthreads();
    #pragma unroll
    for (int k = 0; k < EPB / 1024; ++k) {
        int i4 = blk * (EPB / 4) + k * 256 + t;
        int e = i4 * 4;
        if (e + 3 < E) {
            int4 s4 = ((const int4*)src)[i4];
            int4 d4 = ((const int4*)dst)[i4];
            int p0 = atomicAdd(&cur[d4.x >> 8], 1);
            int p1 = atomicAdd(&cur[d4.y >> 8], 1);
            int p2 = atomicAdd(&cur[d4.z >> 8], 1);
            int p3 = atomicAdd(&cur[d4.w >> 8], 1);
            bedge[p0] = ((unsigned)s4.x << 8) | (unsigned)(d4.x & 255);
            bedge[p1] = ((unsigned)s4.y << 8) | (unsigned)(d4.y & 255);
            bedge[p2] = ((unsigned)s4.z << 8) | (unsigned)(d4.z & 255);
            bedge[p3] = ((unsigned)s4.w << 8) | (unsigned)(d4.w & 255);
        } else {
            for (int j = e; j < E; ++j) {
                int d = dst[j];
                int pos = atomicAdd(&cur[d >> 8], 1);
                bedge[pos] = ((unsigned)src[j] << 8) | (unsigned)(d & 255);
            }
        }
    }
}

// per bucket: per-node histogram+scan -> row_ptr & dinv, then in-bucket placement;
// also folds the batch->gstart boundary detection
__global__ __launch_bounds__(256) void csr_kernel(const unsigned* __restrict__ bedge,
                                                  const int* __restrict__ bbase,
                                                  int* __restrict__ row_ptr,
                                                  float* __restrict__ dinv,
                                                  int* __restrict__ csr_src,
                                                  const int* __restrict__ batch,
                                                  int* __restrict__ gstart,
                                                  int N, int E, int nbk, int NG) {
    __shared__ int cnt[256];
    __shared__ int s[256];
    __shared__ int cur[256];
    int b = blockIdx.x, t = threadIdx.x;
    int node0 = b << 8;
    int beg = bbase[b], end = bbase[b + 1];
    cnt[t] = 0;
    __syncthreads();
    for (int i = beg + t; i < end; i += 256) atomicAdd(&cnt[bedge[i] & 255u], 1);
    __syncthreads();
    int c = cnt[t];
    s[t] = c;
    __syncthreads();
    for (int off = 1; off < 256; off <<= 1) {
        int a = (t >= off) ? s[t - off] : 0;
        __syncthreads();
        s[t] += a;
        __syncthreads();
    }
    int rp = beg + s[t] - c;
    int node = node0 + t;
    if (node < N) {
        row_ptr[node] = rp;
        dinv[node] = rsqrtf((float)c + 1.0f);   // +1 self loop
        int bb = batch[node];
        if (node == 0) {
            gstart[bb] = 0;
            gstart[NG] = N;
        } else if (batch[node - 1] != bb) {
            gstart[bb] = node;
        }
    }
    cur[t] = rp;
    if (b == nbk - 1 && t == 0) row_ptr[N] = E;
    __syncthreads();
    for (int i = beg + t; i < end; i += 256) {
        unsigned u = bedge[i];
        int pos = atomicAdd(&cur[u & 255u], 1);
        csr_src[pos] = (int)(u >> 8);
    }
}

// ---------------- GCN layer ----------------

// H = half( dinv[m] * (X @ W) ) via mfma_f32_16x16x32_f16 (layer 1, X fp32)
__global__ __launch_bounds__(256) void gemm_mfma_kernel(const float* __restrict__ X,
                                                        const _Float16* __restrict__ Bf,
                                                        const float* __restrict__ dinv,
                                                        __half* __restrict__ H, int N) {
    int w = threadIdx.x >> 6;
    int l = threadIdx.x & 63;
    int col = l & 15;
    int kg  = l >> 4;
    int base = blockIdx.x * 64 + w * 16;
    int nodeA = base + col;
    bool okA = nodeA < N;

    f32x4 acc[4] = {};
    #pragma unroll
    for (int c = 0; c < 2; ++c) {
        int k0 = c * 32 + kg * 8;
        f16x8 a = {};
        if (okA) {
            const float* xp = X + (size_t)nodeA * 64 + k0;
            float4 u = *(const float4*)xp;
            float4 v = *(const float4*)(xp + 4);
            a[0] = (_Float16)u.x; a[1] = (_Float16)u.y;
            a[2] = (_Float16)u.z; a[3] = (_Float16)u.w;
            a[4] = (_Float16)v.x; a[5] = (_Float16)v.y;
            a[6] = (_Float16)v.z; a[7] = (_Float16)v.w;
        }
        #pragma unroll
        for (int t = 0; t < 4; ++t) {
            f16x8 b = *(const f16x8*)(Bf + ((size_t)(c * 4 + t) * 64 + l) * 8);
            acc[t] = __builtin_amdgcn_mfma_f32_16x16x32_f16(a, b, acc[t], 0, 0, 0);
        }
    }
    float dvr[4];
    int rowN[4];
    #pragma unroll
    for (int r = 0; r < 4; ++r) {
        rowN[r] = base + kg * 4 + r;
        dvr[r] = (rowN[r] < N) ? dinv[rowN[r]] : 0.0f;
    }
    #pragma unroll
    for (int t = 0; t < 4; ++t) {
        #pragma unroll
        for (int r = 0; r < 4; ++r) {
            if (rowN[r] < N)
                H[(size_t)rowN[r] * 64 + t * 16 + col] = __float2half(acc[t][r] * dvr[r]);
        }
    }
}

#define ACC8(vv, c0, c1, c2, c3, c4, c5, c6, c7)                                \
    { float2 p;                                                                 \
      p = __half22float2((vv).a); c0 += p.x; c1 += p.y;                         \
      p = __half22float2((vv).b); c2 += p.x; c3 += p.y;                         \
      p = __half22float2((vv).c); c4 += p.x; c5 += p.y;                         \
      p = __half22float2((vv).d); c6 += p.x; c7 += p.y; }

// ---- fused layer: agg -> activation -> per-wave MFMA GEMM, no LDS, no barrier ----
// wave = 2 nodes; after the butterfly reduce every lane holds the full sums for its
// feature octet of both nodes, so the wave finishes its own 2 rows of Y@W in-register.
__global__ __launch_bounds__(256) void agg_gemm_kernel(const __half* __restrict__ H,
                                                       const int* __restrict__ rp,
                                                       const int* __restrict__ csrc,
                                                       const float* __restrict__ dinv,
                                                       const float* __restrict__ bias,
                                                       const _Float16* __restrict__ Bf,
                                                       __half* __restrict__ Hout, int N) {
    int w = (blockIdx.x * blockDim.x + threadIdx.x) >> 6;
    int nA = w << 1;
    if (nA >= N) return;                 // wave-uniform
    int nB = nA + 1;
    bool hasB = nB < N;
    int nBs = hasB ? nB : nA;
    int l = threadIdx.x & 63;
    int slot = l >> 3;
    int fo = (l & 7) << 3;
    int endA = rp[nA + 1];
    int eA = rp[nA] + slot;
    int endB = hasB ? rp[nB + 1] : 0;
    int eB = hasB ? (rp[nB] + slot) : 0;
    float a0=0,a1=0,a2=0,a3=0,a4=0,a5=0,a6=0,a7=0;
    float b0=0,b1=0,b2=0,b3=0,b4=0,b5=0,b6=0,b7=0;
    while (eA + 8 < endA && eB + 8 < endB) {
        int sA0 = csrc[eA], sA1 = csrc[eA + 8];
        int sB0 = csrc[eB], sB1 = csrc[eB + 8];
        h8 vA0 = *(const h8*)&H[(size_t)sA0 * 64 + fo];
        h8 vA1 = *(const h8*)&H[(size_t)sA1 * 64 + fo];
        h8 vB0 = *(const h8*)&H[(size_t)sB0 * 64 + fo];
        h8 vB1 = *(const h8*)&H[(size_t)sB1 * 64 + fo];
        ACC8(vA0, a0,a1,a2,a3,a4,a5,a6,a7);
        ACC8(vA1, a0,a1,a2,a3,a4,a5,a6,a7);
        ACC8(vB0, b0,b1,b2,b3,b4,b5,b6,b7);
        ACC8(vB1, b0,b1,b2,b3,b4,b5,b6,b7);
        eA += 16; eB += 16;
    }
    while (eA + 8 < endA) {
        int s0 = csrc[eA], s1 = csrc[eA + 8];
        h8 v0 = *(const h8*)&H[(size_t)s0 * 64 + fo];
        h8 v1 = *(const h8*)&H[(size_t)s1 * 64 + fo];
        ACC8(v0, a0,a1,a2,a3,a4,a5,a6,a7);
        ACC8(v1, a0,a1,a2,a3,a4,a5,a6,a7);
        eA += 16;
    }
    while (eB + 8 < endB) {
        int s0 = csrc[eB], s1 = csrc[eB + 8];
        h8 v0 = *(const h8*)&H[(size_t)s0 * 64 + fo];
        h8 v1 = *(const h8*)&H[(size_t)s1 * 64 + fo];
        ACC8(v0, b0,b1,b2,b3,b4,b5,b6,b7);
        ACC8(v1, b0,b1,b2,b3,b4,b5,b6,b7);
        eB += 16;
    }
    if (eA < endA) {
        h8 v0 = *(const h8*)&H[(size_t)csrc[eA] * 64 + fo];
        ACC8(v0, a0,a1,a2,a3,a4,a5,a6,a7);
    }
    if (eB < endB) {
        h8 v0 = *(const h8*)&H[(size_t)csrc[eB] * 64 + fo];
        ACC8(v0, b0,b1,b2,b3,b4,b5,b6,b7);
    }
    #pragma unroll
    for (int m = 8; m <= 32; m <<= 1) {
        a0 += __shfl_xor(a0, m); a1 += __shfl_xor(a1, m);
        a2 += __shfl_xor(a2, m); a3 += __shfl_xor(a3, m);
        a4 += __shfl_xor(a4, m); a5 += __shfl_xor(a5, m);
        a6 += __shfl_xor(a6, m); a7 += __shfl_xor(a7, m);
        b0 += __shfl_xor(b0, m); b1 += __shfl_xor(b1, m);
        b2 += __shfl_xor(b2, m); b3 += __shfl_xor(b3, m);
        b4 += __shfl_xor(b4, m); b5 += __shfl_xor(b5, m);
        b6 += __shfl_xor(b6, m); b7 += __shfl_xor(b7, m);
    }
    // activation in ALL lanes (each lane: octet fo of both nodes), pack to fp16 pairs
    float4 bv0 = *(const float4*)&bias[fo];
    float4 bv1 = *(const float4*)&bias[fo + 4];
    int pa[4], pb[4];
    {
        h8 hs = *(const h8*)&H[(size_t)nA * 64 + fo];
        float2 s0 = __half22float2(hs.a), s1 = __half22float2(hs.b);
        float2 s2 = __half22float2(hs.c), s3 = __half22float2(hs.d);
        float dv = dinv[nA];
        __half2 q0 = __floats2half2_rn(LRELU(dv * (a0 + s0.x) + bv0.x),
                                       LRELU(dv * (a1 + s0.y) + bv0.y));
        __half2 q1 = __floats2half2_rn(LRELU(dv * (a2 + s1.x) + bv0.z),
                                       LRELU(dv * (a3 + s1.y) + bv0.w));
        __half2 q2 = __floats2half2_rn(LRELU(dv * (a4 + s2.x) + bv1.x),
                                       LRELU(dv * (a5 + s2.y) + bv1.y));
        __half2 q3 = __floats2half2_rn(LRELU(dv * (a6 + s3.x) + bv1.z),
                                       LRELU(dv * (a7 + s3.y) + bv1.w));
        pa[0] = *(int*)&q0; pa[1] = *(int*)&q1; pa[2] = *(int*)&q2; pa[3] = *(int*)&q3;
    }
    {
        h8 hs = *(const h8*)&H[(size_t)nBs * 64 + fo];
        float2 s0 = __half22float2(hs.a), s1 = __half22float2(hs.b);
        float2 s2 = __half22float2(hs.c), s3 = __half22float2(hs.d);
        float dv = dinv[nBs];
        __half2 q0 = __floats2half2_rn(LRELU(dv * (b0 + s0.x) + bv0.x),
                                       LRELU(dv * (b1 + s0.y) + bv0.y));
        __half2 q1 = __floats2half2_rn(LRELU(dv * (b2 + s1.x) + bv0.z),
                                       LRELU(dv * (b3 + s1.y) + bv0.w));
        __half2 q2 = __floats2half2_rn(LRELU(dv * (b4 + s2.x) + bv1.x),
                                       LRELU(dv * (b5 + s2.y) + bv1.y));
        __half2 q3 = __floats2half2_rn(LRELU(dv * (b6 + s3.x) + bv1.z),
                                       LRELU(dv * (b7 + s3.y) + bv1.w));
        pb[0] = *(int*)&q0; pb[1] = *(int*)&q1; pb[2] = *(int*)&q2; pb[3] = *(int*)&q3;
    }
    // per-wave GEMM: A row (l&15): 0 = nA, 1 = nB (rows >=2 garbage, never stored)
    bool rowB = (l & 15) == 1;
    int oct = l >> 4;                 // kg
    f32x4 acc[4] = {};
    #pragma unroll
    for (int c = 0; c < 2; ++c) {
        int so = c * 4 + oct;         // source octet = lane (l&7)==so
        union { int u[4]; f16x8 v; } af;
        #pragma unroll
        for (int j = 0; j < 4; ++j) {
            int qa = __shfl(pa[j], so);
            int qb = __shfl(pb[j], so);
            af.u[j] = rowB ? qb : qa;
        }
        #pragma unroll
        for (int t = 0; t < 4; ++t) {
            f16x8 b = *(const f16x8*)(Bf + ((size_t)(c * 4 + t) * 64 + l) * 8);
            acc[t] = __builtin_amdgcn_mfma_f32_16x16x32_f16(af.v, b, acc[t], 0, 0, 0);
        }
    }
    // C: row = (l>>4)*4 + r, col = l&15 -> rows 0,1 live in lanes 0..15, regs 0,1
    if (l < 16) {
        float dvA = dinv[nA];
        #pragma unroll
        for (int t = 0; t < 4; ++t)
            Hout[(size_t)nA * 64 + t * 16 + l] = __float2half(acc[t][0] * dvA);
        if (hasB) {
            float dvB = dinv[nB];
            #pragma unroll
            for (int t = 0; t < 4; ++t)
                Hout[(size_t)nB * 64 + t * 16 + l] = __float2half(acc[t][1] * dvB);
        }
    }
}

// layer 3: Y = leaky(dinv*(agg)+bias) to global (fp16), feeds pooling
__global__ __launch_bounds__(256) void agg_kernel(const __half* __restrict__ H,
                                                  const int* __restrict__ rp,
                                                  const int* __restrict__ csrc,
                                                  const float* __restrict__ dinv,
                                                  const float* __restrict__ bias,
                                                  __half* __restrict__ Y, int N) {
    int w = (blockIdx.x * blockDim.x + threadIdx.x) >> 6;
    int nA = w << 1;
    if (nA >= N) return;
    int nB = nA + 1;
    bool hasB = nB < N;
    int l = threadIdx.x & 63;
    int slot = l >> 3;
    int fo = (l & 7) << 3;
    int endA = rp[nA + 1];
    int eA = rp[nA] + slot;
    int endB = hasB ? rp[nB + 1] : 0;
    int eB = hasB ? (rp[nB] + slot) : 0;
    float a0=0,a1=0,a2=0,a3=0,a4=0,a5=0,a6=0,a7=0;
    float b0=0,b1=0,b2=0,b3=0,b4=0,b5=0,b6=0,b7=0;
    while (eA + 8 < endA && eB + 8 < endB) {
        int sA0 = csrc[eA], sA1 = csrc[eA + 8];
        int sB0 = csrc[eB], sB1 = csrc[eB + 8];
        h8 vA0 = *(const h8*)&H[(size_t)sA0 * 64 + fo];
        h8 vA1 = *(const h8*)&H[(size_t)sA1 * 64 + fo];
        h8 vB0 = *(const h8*)&H[(size_t)sB0 * 64 + fo];
        h8 vB1 = *(const h8*)&H[(size_t)sB1 * 64 + fo];
        ACC8(vA0, a0,a1,a2,a3,a4,a5,a6,a7);
        ACC8(vA1, a0,a1,a2,a3,a4,a5,a6,a7);
        ACC8(vB0, b0,b1,b2,b3,b4,b5,b6,b7);
        ACC8(vB1, b0,b1,b2,b3,b4,b5,b6,b7);
        eA += 16; eB += 16;
    }
    while (eA + 8 < endA) {
        int s0 = csrc[eA], s1 = csrc[eA + 8];
        h8 v0 = *(const h8*)&H[(size_t)s0 * 64 + fo];
        h8 v1 = *(const h8*)&H[(size_t)s1 * 64 + fo];
        ACC8(v0, a0,a1,a2,a3,a4,a5,a6,a7);
        ACC8(v1, a0,a1,a2,a3,a4,a5,a6,a7);
        eA += 16;
    }
    while (eB + 8 < endB) {
        int s0 = csrc[eB], s1 = csrc[eB + 8];
        h8 v0 = *(const h8*)&H[(size_t)s0 * 64 + fo];
        h8 v1 = *(const h8*)&H[(size_t)s1 * 64 + fo];
        ACC8(v0, b0,b1,b2,b3,b4,b5,b6,b7);
        ACC8(v1, b0,b1,b2,b3,b4,b5,b6,b7);
        eB += 16;
    }
    if (eA < endA) {
        h8 v0 = *(const h8*)&H[(size_t)csrc[eA] * 64 + fo];
        ACC8(v0, a0,a1,a2,a3,a4,a5,a6,a7);
    }
    if (eB < endB) {
        h8 v0 = *(const h8*)&H[(size_t)csrc[eB] * 64 + fo];
        ACC8(v0, b0,b1,b2,b3,b4,b5,b6,b7);
    }
    #pragma unroll
    for (int m = 8; m <= 32; m <<= 1) {
        a0 += __shfl_xor(a0, m); a1 += __shfl_xor(a1, m);
        a2 += __shfl_xor(a2, m); a3 += __shfl_xor(a3, m);
        a4 += __shfl_xor(a4, m); a5 += __shfl_xor(a5, m);
        a6 += __shfl_xor(a6, m); a7 += __shfl_xor(a7, m);
        b0 += __shfl_xor(b0, m); b1 += __shfl_xor(b1, m);
        b2 += __shfl_xor(b2, m); b3 += __shfl_xor(b3, m);
        b4 += __shfl_xor(b4, m); b5 += __shfl_xor(b5, m);
        b6 += __shfl_xor(b6, m); b7 += __shfl_xor(b7, m);
    }
    if (l < 8) {
        float4 bv0 = *(const float4*)&bias[fo];
        float4 bv1 = *(const float4*)&bias[fo + 4];
        {
            h8 hs = *(const h8*)&H[(size_t)nA * 64 + fo];
            float2 s0 = __half22float2(hs.a), s1 = __half22float2(hs.b);
            float2 s2 = __half22float2(hs.c), s3 = __half22float2(hs.d);
            float dv = dinv[nA];
            float o0 = LRELU(dv * (a0 + s0.x) + bv0.x);
            float o1 = LRELU(dv * (a1 + s0.y) + bv0.y);
            float o2 = LRELU(dv * (a2 + s1.x) + bv0.z);
            float o3 = LRELU(dv * (a3 + s1.y) + bv0.w);
            float o4 = LRELU(dv * (a4 + s2.x) + bv1.x);
            float o5 = LRELU(dv * (a5 + s2.y) + bv1.y);
            float o6 = LRELU(dv * (a6 + s3.x) + bv1.z);
            float o7 = LRELU(dv * (a7 + s3.y) + bv1.w);
            h8 o;
            o.a = __floats2half2_rn(o0, o1);
            o.b = __floats2half2_rn(o2, o3);
            o.c = __floats2half2_rn(o4, o5);
            o.d = __floats2half2_rn(o6, o7);
            *(h8*)&Y[(size_t)nA * 64 + fo] = o;
        }
        if (hasB) {
            h8 hs = *(const h8*)&H[(size_t)nB * 64 + fo];
            float2 s0 = __half22float2(hs.a), s1 = __half22float2(hs.b);
            float2 s2 = __half22float2(hs.c), s3 = __half22float2(hs.d);
            float dv = dinv[nB];
            float o0 = LRELU(dv * (b0 + s0.x) + bv0.x);
            float o1 = LRELU(dv * (b1 + s0.y) + bv0.y);
            float o2 = LRELU(dv * (b2 + s1.x) + bv0.z);
            float o3 = LRELU(dv * (b3 + s1.y) + bv0.w);
            float o4 = LRELU(dv * (b4 + s2.x) + bv1.x);
            float o5 = LRELU(dv * (b5 + s2.y) + bv1.y);
            float o6 = LRELU(dv * (b6 + s3.x) + bv1.z);
            float o7 = LRELU(dv * (b7 + s3.y) + bv1.w);
            h8 o;
            o.a = __floats2half2_rn(o0, o1);
            o.b = __floats2half2_rn(o2, o3);
            o.c = __floats2half2_rn(o4, o5);
            o.d = __floats2half2_rn(o6, o7);
            *(h8*)&Y[(size_t)nB * 64 + fo] = o;
        }
    }
}

// ---------------- pooling + MLP ----------------

__global__ __launch_bounds__(256) void pool1_kernel(const __half* __restrict__ Y,
                                                    const int* __restrict__ gstart,
                                                    float* __restrict__ pbuf) {
    __shared__ float ssum[8][64];
    __shared__ float smax[8][64];
    int g = blockIdx.x / PARTS;
    int p = blockIdx.x % PARTS;
    int t = threadIdx.x;
    int f2 = (t & 31) * 2;
    int rg = t >> 5;
    int s = gstart[g], epos = gstart[g + 1];
    int len = epos - s;
    int lo = s + (int)((long long)len * p / PARTS);
    int hi = s + (int)((long long)len * (p + 1) / PARTS);
    float sx = 0.f, sy = 0.f, mx = -3.0e38f, my = -3.0e38f;
    for (int r = lo + rg; r < hi; r += 8) {
        __half2 v = *(const __half2*)&Y[(size_t)r * 64 + f2];
        float2 f = __half22float2(v);
        sx += f.x; sy += f.y;
        mx = fmaxf(mx, f.x); my = fmaxf(my, f.y);
    }
    ssum[rg][f2] = sx; ssum[rg][f2 + 1] = sy;
    smax[rg][f2] = mx; smax[rg][f2 + 1] = my;
    __syncthreads();
    if (t < 64) {
        float ts = 0.f, tm = -3.0e38f;
        #pragma unroll
        for (int r = 0; r < 8; ++r) {
            ts += ssum[r][t];
            tm = fmaxf(tm, smax[r][t]);
        }
        float* row = &pbuf[(size_t)(g * PARTS + p) * 128];
        row[t] = ts;
        row[64 + t] = tm;
    }
}

__global__ __launch_bounds__(256) void mlp_kernel(const float* __restrict__ pbuf,
                                                  const int* __restrict__ gstart,
                                                  const float* __restrict__ gfeat,
                                                  const float* __restrict__ w1,
                                                  const float* __restrict__ b1,
                                                  const float* __restrict__ w2,
                                                  const float* __restrict__ b2,
                                                  const float* __restrict__ w3,
                                                  const float* __restrict__ b3,
                                                  float* __restrict__ out, int NG) {
    __shared__ float hl[160];
    __shared__ float h1[256];
    __shared__ float red[128];
    int g = blockIdx.x, t = threadIdx.x;
    if (t < 64) {
        const float* base = &pbuf[(size_t)g * PARTS * 128];
        float ts = 0.f, tm = -3.0e38f;
        #pragma unroll
        for (int p = 0; p < PARTS; ++p) {
            ts += base[p * 128 + t];
            tm = fmaxf(tm, base[p * 128 + 64 + t]);
        }
        float cnt = (float)(gstart[g + 1] - gstart[g]);
        hl[t] = ts / cnt;
        hl[64 + t] = tm;
    } else if (t >= 128 && t < 160) {
        hl[t] = gfeat[g * 32 + (t - 128)];
    }
    __syncthreads();
    float a1 = b1[t];
    for (int k = 0; k < 160; ++k) a1 += hl[k] * w1[k * 256 + t];
    h1[t] = LRELU(a1);
    __syncthreads();
    if (t < 128) {
        float a2 = b2[t];
        for (int k = 0; k < 256; ++k) a2 += h1[k] * w2[k * 128 + t];
        red[t] = LRELU(a2) * w3[t];
    }
    __syncthreads();
    if (t == 0) {
        float a3 = b3[0];
        for (int k = 0; k < 128; ++k) a3 += red[k];
        out[g] = a3;
    }
}

// ---------------- launch ----------------

extern "C" void kernel_launch(void* const* d_in, const int* in_sizes, int n_in,
                              void* d_out, int out_size, void* d_ws, size_t ws_size,
                              hipStream_t stream) {
    const float* x      = (const float*)d_in[0];
    const float* gfeat  = (const float*)d_in[1];
    const float* cw1    = (const float*)d_in[2];
    const float* cb1    = (const float*)d_in[3];
    const float* cw2    = (const float*)d_in[4];
    const float* cb2    = (const float*)d_in[5];
    const float* cw3    = (const float*)d_in[6];
    const float* cb3    = (const float*)d_in[7];
    const float* fw1    = (const float*)d_in[8];
    const float* fb1    = (const float*)d_in[9];
    const float* fw2    = (const float*)d_in[10];
    const float* fb2    = (const float*)d_in[11];
    const float* ow     = (const float*)d_in[12];
    const float* ob     = (const float*)d_in[13];
    const int*   eidx   = (const int*)d_in[14];
    const int*   batch  = (const int*)d_in[15];

    const int N    = in_sizes[0] / 64;
    const int E    = in_sizes[14] / 2;
    const int NG   = in_sizes[1] / 32;
    const int NBUK = (N + 255) >> 8;          // dst buckets of 256 nodes
    const int NBLK = (E + EPB - 1) / EPB;     // sort blocks
    const int* src = eidx;
    const int* dst = eidx + E;

    // workspace carve-out (256B aligned)
    char* wp = (char*)d_ws;
    auto carve = [&](size_t bytes) {
        void* p = (void*)wp;
        wp += (bytes + 255) & ~(size_t)255;
        return p;
    };
    float*     dinv    = (float*)    carve((size_t)N * 4);
    int*       row_ptr = (int*)      carve((size_t)(N + 1) * 4);
    int*       bhist   = (int*)      carve((size_t)NBUK * NBLK * 4);
    int*       btot    = (int*)      carve((size_t)NBUK * 4);
    int*       bbase   = (int*)      carve((size_t)(NBUK + 1) * 4);
    unsigned*  bedge   = (unsigned*) carve((size_t)E * 4);
    int*       csr_src = (int*)      carve((size_t)E * 4);
    __half*    hA      = (__half*)   carve((size_t)N * 64 * 2);
    __half*    hB      = (__half*)   carve((size_t)N * 64 * 2);
    __half*    ybuf    = (__half*)   carve((size_t)N * 64 * 2);
    int*       gstart  = (int*)      carve((size_t)(NG + 1) * 4);
    float*     pbuf    = (float*)    carve((size_t)NG * PARTS * 128 * 4);
    _Float16*  Bf      = (_Float16*) carve((size_t)3 * 4096 * 2);
    float*     outf    = (float*)d_out;

    hist1_kernel<<<NBLK, 256, 0, stream>>>(dst, bhist, NBLK, E, NBUK);
    scanb_kernel<<<NBUK, 256, 0, stream>>>(bhist, btot, NBLK);
    bbase_wprep_kernel<<<7, 512, 0, stream>>>(btot, bbase, NBUK, E, cw1, cw2, cw3, Bf);
    place_kernel<<<NBLK, 256, 0, stream>>>(src, dst, bbase, bhist, bedge, NBLK, E, NBUK);
    csr_kernel<<<NBUK, 256, 0, stream>>>(bedge, bbase, row_ptr, dinv, csr_src,
                                         batch, gstart, N, E, NBUK, NG);

    const int gemmB = (N + 63) / 64;
    const int aggB  = ((N + 1) / 2 + 3) / 4;   // 2 nodes per wave, 4 waves per block

    gemm_mfma_kernel<<<gemmB, 256, 0, stream>>>(x, Bf, dinv, hA, N);
    agg_gemm_kernel<<<aggB, 256, 0, stream>>>(hA, row_ptr, csr_src, dinv, cb1,
                                              Bf + 4096, hB, N);
    agg_gemm_kernel<<<aggB, 256, 0, stream>>>(hB, row_ptr, csr_src, dinv, cb2,
                                              Bf + 8192, hA, N);
    agg_kernel<<<aggB, 256, 0, stream>>>(hA, row_ptr, csr_src, dinv, cb3, ybuf, N);

    pool1_kernel<<<NG * PARTS, 256, 0, stream>>>(ybuf, gstart, pbuf);
    mlp_kernel<<<NG, 256, 0, stream>>>(pbuf, gstart, gfeat, fw1, fb1, fw2, fb2, ow, ob, outf, NG);
}

// Round 12
// 211.699 us; speedup vs baseline: 1.0335x; 1.0335x over previous
//
#include <hip/hip_runtime.h>
#include <hip/hip_fp16.h>
#include <stdint.h>

#define LRELU(x) ((x) > 0.0f ? (x) : 0.01f * (x))

struct h4 { __half2 a, b; };          // 4 fp16, 8 B
struct h8 { __half2 a, b, c, d; };    // 8 fp16, 16 B

typedef _Float16 f16x8 __attribute__((ext_vector_type(8)));
typedef float    f32x4 __attribute__((ext_vector_type(4)));

#define EPB 8192                      // edges per block in sort passes
#define PARTS 16                      // pooling sub-slices per graph

// ---------------- CSR build: deterministic counting sort, no global atomics ----------------

__global__ __launch_bounds__(256) void hist1_kernel(const int* __restrict__ dst,
                                                    int* __restrict__ bhist,
                                                    int nblk, int E, int nbk) {
    __shared__ int h[512];
    int blk = blockIdx.x, t = threadIdx.x;
    for (int i = t; i < nbk; i += 256) h[i] = 0;
    __syncthreads();
    #pragma unroll
    for (int k = 0; k < EPB / 1024; ++k) {
        int i4 = blk * (EPB / 4) + k * 256 + t;
        int e = i4 * 4;
        if (e + 3 < E) {
            int4 d = ((const int4*)dst)[i4];
            atomicAdd(&h[d.x >> 8], 1);
            atomicAdd(&h[d.y >> 8], 1);
            atomicAdd(&h[d.z >> 8], 1);
            atomicAdd(&h[d.w >> 8], 1);
        } else {
            for (int j = e; j < E; ++j) atomicAdd(&h[dst[j] >> 8], 1);
        }
    }
    __syncthreads();
    for (int i = t; i < nbk; i += 256) bhist[i * nblk + blk] = h[i];
}

__global__ __launch_bounds__(256) void scanb_kernel(int* __restrict__ bhist,
                                                    int* __restrict__ btot, int nblk) {
    __shared__ int s[256];
    __shared__ int carry;
    int b = blockIdx.x, t = threadIdx.x;
    if (t == 0) carry = 0;
    __syncthreads();
    for (int c0 = 0; c0 < nblk; c0 += 256) {
        int idx = c0 + t;
        int v = (idx < nblk) ? bhist[b * nblk + idx] : 0;
        s[t] = v;
        __syncthreads();
        for (int off = 1; off < 256; off <<= 1) {
            int a = (t >= off) ? s[t - off] : 0;
            __syncthreads();
            s[t] += a;
            __syncthreads();
        }
        if (idx < nblk) bhist[b * nblk + idx] = s[t] - v + carry;
        __syncthreads();
        if (t == 255) carry += s[255];
        __syncthreads();
    }
    if (t == 0) btot[b] = carry;
}

// block 0: exclusive scan of bucket totals -> bbase
// blocks 1..6: cast W (fp32 [64][64]) into per-lane MFMA B-fragment order (fp16)
__global__ __launch_bounds__(512) void bbase_wprep_kernel(const int* __restrict__ btot,
                                                          int* __restrict__ bbase,
                                                          int nbk, int E,
                                                          const float* __restrict__ w1,
                                                          const float* __restrict__ w2,
                                                          const float* __restrict__ w3,
                                                          _Float16* __restrict__ Bf) {
    if (blockIdx.x == 0) {
        __shared__ int s[512];
        int t = threadIdx.x;
        int v = (t < nbk) ? btot[t] : 0;
        s[t] = v;
        __syncthreads();
        for (int off = 1; off < 512; off <<= 1) {
            int a = (t >= off) ? s[t - off] : 0;
            __syncthreads();
            s[t] += a;
            __syncthreads();
        }
        if (t < nbk) bbase[t] = s[t] - v;
        if (t == 0) bbase[nbk] = E;
    } else {
        int bc = blockIdx.x - 1;        // 0..5 = layer*2 + c
        int tid = threadIdx.x;
        if (tid < 256) {
            int layer = bc >> 1, c = bc & 1;
            const float* W = (layer == 0) ? w1 : ((layer == 1) ? w2 : w3);
            int t = tid >> 6, l = tid & 63;
            _Float16* dstp = Bf + ((size_t)(layer * 8 + c * 4 + t) * 64 + l) * 8;
            int n  = t * 16 + (l & 15);
            int kb = c * 32 + (l >> 4) * 8;
            #pragma unroll
            for (int i = 0; i < 8; ++i) dstp[i] = (_Float16)W[(kb + i) * 64 + n];
        }
    }
}

__global__ __launch_bounds__(256) void place_kernel(const int* __restrict__ src,
                                                    const int* __restrict__ dst,
                                                    const int* __restrict__ bbase,
                                                    const int* __restrict__ bhist,
                                                    unsigned* __restrict__ bedge,
                                                    int nblk, int E, int nbk) {
    __shared__ int cur[512];
    int blk = blockIdx.x, t = threadIdx.x;
    for (int i = t; i < nbk; i += 256) cur[i] = bbase[i] + bhist[i * nblk + blk];
    __syncthreads();
    #pragma unroll
    for (int k = 0; k < EPB / 1024; ++k) {
        int i4 = blk * (EPB / 4) + k * 256 + t;
        int e = i4 * 4;
        if (e + 3 < E) {
            int4 s4 = ((const int4*)src)[i4];
            int4 d4 = ((const int4*)dst)[i4];
            int p0 = atomicAdd(&cur[d4.x >> 8], 1);
            int p1 = atomicAdd(&cur[d4.y >> 8], 1);
            int p2 = atomicAdd(&cur[d4.z >> 8], 1);
            int p3 = atomicAdd(&cur[d4.w >> 8], 1);
            bedge[p0] = ((unsigned)s4.x << 8) | (unsigned)(d4.x & 255);
            bedge[p1] = ((unsigned)s4.y << 8) | (unsigned)(d4.y & 255);
            bedge[p2] = ((unsigned)s4.z << 8) | (unsigned)(d4.z & 255);
            bedge[p3] = ((unsigned)s4.w << 8) | (unsigned)(d4.w & 255);
        } else {
            for (int j = e; j < E; ++j) {
                int d = dst[j];
                int pos = atomicAdd(&cur[d >> 8], 1);
                bedge[pos] = ((unsigned)src[j] << 8) | (unsigned)(d & 255);
            }
        }
    }
}

// per bucket: per-node histogram+scan -> row_ptr & dinv, then in-bucket placement;
// also folds the batch->gstart boundary detection
__global__ __launch_bounds__(256) void csr_kernel(const unsigned* __restrict__ bedge,
                                                  const int* __restrict__ bbase,
                                                  int* __restrict__ row_ptr,
                                                  float* __restrict__ dinv,
                                                  int* __restrict__ csr_src,
                                                  const int* __restrict__ batch,
                                                  int* __restrict__ gstart,
                                                  int N, int E, int nbk, int NG) {
    __shared__ int cnt[256];
    __shared__ int s[256];
    __shared__ int cur[256];
    int b = blockIdx.x, t = threadIdx.x;
    int node0 = b << 8;
    int beg = bbase[b], end = bbase[b + 1];
    cnt[t] = 0;
    __syncthreads();
    for (int i = beg + t; i < end; i += 256) atomicAdd(&cnt[bedge[i] & 255u], 1);
    __syncthreads();
    int c = cnt[t];
    s[t] = c;
    __syncthreads();
    for (int off = 1; off < 256; off <<= 1) {
        int a = (t >= off) ? s[t - off] : 0;
        __syncthreads();
        s[t] += a;
        __syncthreads();
    }
    int rp = beg + s[t] - c;
    int node = node0 + t;
    if (node < N) {
        row_ptr[node] = rp;
        dinv[node] = rsqrtf((float)c + 1.0f);   // +1 self loop
        int bb = batch[node];
        if (node == 0) {
            gstart[bb] = 0;
            gstart[NG] = N;
        } else if (batch[node - 1] != bb) {
            gstart[bb] = node;
        }
    }
    cur[t] = rp;
    if (b == nbk - 1 && t == 0) row_ptr[N] = E;
    __syncthreads();
    for (int i = beg + t; i < end; i += 256) {
        unsigned u = bedge[i];
        int pos = atomicAdd(&cur[u & 255u], 1);
        csr_src[pos] = (int)(u >> 8);
    }
}

// ---------------- GCN layer ----------------

// H = half( dinv[m] * (X @ W) ) via mfma_f32_16x16x32_f16 (layer 1, X fp32)
__global__ __launch_bounds__(256) void gemm_mfma_kernel(const float* __restrict__ X,
                                                        const _Float16* __restrict__ Bf,
                                                        const float* __restrict__ dinv,
                                                        __half* __restrict__ H, int N) {
    int w = threadIdx.x >> 6;
    int l = threadIdx.x & 63;
    int col = l & 15;
    int kg  = l >> 4;
    int base = blockIdx.x * 64 + w * 16;
    int nodeA = base + col;
    bool okA = nodeA < N;

    f32x4 acc[4] = {};
    #pragma unroll
    for (int c = 0; c < 2; ++c) {
        int k0 = c * 32 + kg * 8;
        f16x8 a = {};
        if (okA) {
            const float* xp = X + (size_t)nodeA * 64 + k0;
            float4 u = *(const float4*)xp;
            float4 v = *(const float4*)(xp + 4);
            a[0] = (_Float16)u.x; a[1] = (_Float16)u.y;
            a[2] = (_Float16)u.z; a[3] = (_Float16)u.w;
            a[4] = (_Float16)v.x; a[5] = (_Float16)v.y;
            a[6] = (_Float16)v.z; a[7] = (_Float16)v.w;
        }
        #pragma unroll
        for (int t = 0; t < 4; ++t) {
            f16x8 b = *(const f16x8*)(Bf + ((size_t)(c * 4 + t) * 64 + l) * 8);
            acc[t] = __builtin_amdgcn_mfma_f32_16x16x32_f16(a, b, acc[t], 0, 0, 0);
        }
    }
    float dvr[4];
    int rowN[4];
    #pragma unroll
    for (int r = 0; r < 4; ++r) {
        rowN[r] = base + kg * 4 + r;
        dvr[r] = (rowN[r] < N) ? dinv[rowN[r]] : 0.0f;
    }
    #pragma unroll
    for (int t = 0; t < 4; ++t) {
        #pragma unroll
        for (int r = 0; r < 4; ++r) {
            if (rowN[r] < N)
                H[(size_t)rowN[r] * 64 + t * 16 + col] = __float2half(acc[t][r] * dvr[r]);
        }
    }
}

#define ACC8(vv, c0, c1, c2, c3, c4, c5, c6, c7)                                \
    { float2 p;                                                                 \
      p = __half22float2((vv).a); c0 += p.x; c1 += p.y;                         \
      p = __half22float2((vv).b); c2 += p.x; c3 += p.y;                         \
      p = __half22float2((vv).c); c4 += p.x; c5 += p.y;                         \
      p = __half22float2((vv).d); c6 += p.x; c7 += p.y; }

// ---- fused layer: Y = leaky(dinv*(agg)+bias) -> LDS -> H' = half(dinv*(Y@W')) ----
// 8 waves x 2 nodes = 16 nodes/block; waves 0-3 run the MFMA tile afterwards.
__global__ __launch_bounds__(512) void agg_gemm_kernel(const __half* __restrict__ H,
                                                       const int* __restrict__ rp,
                                                       const int* __restrict__ csrc,
                                                       const float* __restrict__ dinv,
                                                       const float* __restrict__ bias,
                                                       const _Float16* __restrict__ Bf,
                                                       __half* __restrict__ Hout, int N) {
    __shared__ _Float16 ylds[16][72];   // 144 B rows: 16B-aligned, <=2-way bank alias
    int wv = threadIdx.x >> 6;
    int l  = threadIdx.x & 63;
    int base = blockIdx.x * 16;
    int nA = base + wv * 2;
    int nB = nA + 1;
    bool hasA = nA < N;
    bool hasB = nB < N;
    int slot = l >> 3;
    int fo = (l & 7) << 3;
    float a0=0,a1=0,a2=0,a3=0,a4=0,a5=0,a6=0,a7=0;
    float b0=0,b1=0,b2=0,b3=0,b4=0,b5=0,b6=0,b7=0;
    if (hasA) {                          // wave-uniform guard
        int endA = rp[nA + 1];
        int eA = rp[nA] + slot;
        int endB = hasB ? rp[nB + 1] : 0;
        int eB = hasB ? (rp[nB] + slot) : 0;
        while (eA + 8 < endA && eB + 8 < endB) {
            int sA0 = csrc[eA], sA1 = csrc[eA + 8];
            int sB0 = csrc[eB], sB1 = csrc[eB + 8];
            h8 vA0 = *(const h8*)&H[(size_t)sA0 * 64 + fo];
            h8 vA1 = *(const h8*)&H[(size_t)sA1 * 64 + fo];
            h8 vB0 = *(const h8*)&H[(size_t)sB0 * 64 + fo];
            h8 vB1 = *(const h8*)&H[(size_t)sB1 * 64 + fo];
            ACC8(vA0, a0,a1,a2,a3,a4,a5,a6,a7);
            ACC8(vA1, a0,a1,a2,a3,a4,a5,a6,a7);
            ACC8(vB0, b0,b1,b2,b3,b4,b5,b6,b7);
            ACC8(vB1, b0,b1,b2,b3,b4,b5,b6,b7);
            eA += 16; eB += 16;
        }
        while (eA + 8 < endA) {
            int s0 = csrc[eA], s1 = csrc[eA + 8];
            h8 v0 = *(const h8*)&H[(size_t)s0 * 64 + fo];
            h8 v1 = *(const h8*)&H[(size_t)s1 * 64 + fo];
            ACC8(v0, a0,a1,a2,a3,a4,a5,a6,a7);
            ACC8(v1, a0,a1,a2,a3,a4,a5,a6,a7);
            eA += 16;
        }
        while (eB + 8 < endB) {
            int s0 = csrc[eB], s1 = csrc[eB + 8];
            h8 v0 = *(const h8*)&H[(size_t)s0 * 64 + fo];
            h8 v1 = *(const h8*)&H[(size_t)s1 * 64 + fo];
            ACC8(v0, b0,b1,b2,b3,b4,b5,b6,b7);
            ACC8(v1, b0,b1,b2,b3,b4,b5,b6,b7);
            eB += 16;
        }
        if (eA < endA) {
            h8 v0 = *(const h8*)&H[(size_t)csrc[eA] * 64 + fo];
            ACC8(v0, a0,a1,a2,a3,a4,a5,a6,a7);
        }
        if (eB < endB) {
            h8 v0 = *(const h8*)&H[(size_t)csrc[eB] * 64 + fo];
            ACC8(v0, b0,b1,b2,b3,b4,b5,b6,b7);
        }
        #pragma unroll
        for (int m = 8; m <= 32; m <<= 1) {
            a0 += __shfl_xor(a0, m); a1 += __shfl_xor(a1, m);
            a2 += __shfl_xor(a2, m); a3 += __shfl_xor(a3, m);
            a4 += __shfl_xor(a4, m); a5 += __shfl_xor(a5, m);
            a6 += __shfl_xor(a6, m); a7 += __shfl_xor(a7, m);
            b0 += __shfl_xor(b0, m); b1 += __shfl_xor(b1, m);
            b2 += __shfl_xor(b2, m); b3 += __shfl_xor(b3, m);
            b4 += __shfl_xor(b4, m); b5 += __shfl_xor(b5, m);
            b6 += __shfl_xor(b6, m); b7 += __shfl_xor(b7, m);
        }
        if (l < 8) {
            float4 bv0 = *(const float4*)&bias[fo];
            float4 bv1 = *(const float4*)&bias[fo + 4];
            {
                h8 hs = *(const h8*)&H[(size_t)nA * 64 + fo];
                float2 s0 = __half22float2(hs.a), s1 = __half22float2(hs.b);
                float2 s2 = __half22float2(hs.c), s3 = __half22float2(hs.d);
                float dv = dinv[nA];
                _Float16* yp = &ylds[wv * 2][fo];
                yp[0] = (_Float16)(LRELU(dv * (a0 + s0.x) + bv0.x));
                yp[1] = (_Float16)(LRELU(dv * (a1 + s0.y) + bv0.y));
                yp[2] = (_Float16)(LRELU(dv * (a2 + s1.x) + bv0.z));
                yp[3] = (_Float16)(LRELU(dv * (a3 + s1.y) + bv0.w));
                yp[4] = (_Float16)(LRELU(dv * (a4 + s2.x) + bv1.x));
                yp[5] = (_Float16)(LRELU(dv * (a5 + s2.y) + bv1.y));
                yp[6] = (_Float16)(LRELU(dv * (a6 + s3.x) + bv1.z));
                yp[7] = (_Float16)(LRELU(dv * (a7 + s3.y) + bv1.w));
            }
            if (hasB) {
                h8 hs = *(const h8*)&H[(size_t)nB * 64 + fo];
                float2 s0 = __half22float2(hs.a), s1 = __half22float2(hs.b);
                float2 s2 = __half22float2(hs.c), s3 = __half22float2(hs.d);
                float dv = dinv[nB];
                _Float16* yp = &ylds[wv * 2 + 1][fo];
                yp[0] = (_Float16)(LRELU(dv * (b0 + s0.x) + bv0.x));
                yp[1] = (_Float16)(LRELU(dv * (b1 + s0.y) + bv0.y));
                yp[2] = (_Float16)(LRELU(dv * (b2 + s1.x) + bv0.z));
                yp[3] = (_Float16)(LRELU(dv * (b3 + s1.y) + bv0.w));
                yp[4] = (_Float16)(LRELU(dv * (b4 + s2.x) + bv1.x));
                yp[5] = (_Float16)(LRELU(dv * (b5 + s2.y) + bv1.y));
                yp[6] = (_Float16)(LRELU(dv * (b6 + s3.x) + bv1.z));
                yp[7] = (_Float16)(LRELU(dv * (b7 + s3.y) + bv1.w));
            }
        }
    }
    __syncthreads();
    // GEMM phase: waves 0-3, wave t computes output columns t*16..t*16+15.
    // Garbage in ylds rows >= N is harmless: C row i depends only on A row i.
    if (wv < 4) {
        int col = l & 15;
        int kg  = l >> 4;
        f32x4 acc = {};
        #pragma unroll
        for (int c = 0; c < 2; ++c) {
            f16x8 a = *(const f16x8*)&ylds[col][c * 32 + kg * 8];
            f16x8 b = *(const f16x8*)(Bf + ((size_t)(c * 4 + wv) * 64 + l) * 8);
            acc = __builtin_amdgcn_mfma_f32_16x16x32_f16(a, b, acc, 0, 0, 0);
        }
        #pragma unroll
        for (int r = 0; r < 4; ++r) {
            int row = base + kg * 4 + r;
            if (row < N)
                Hout[(size_t)row * 64 + wv * 16 + col] = __float2half(acc[r] * dinv[row]);
        }
    }
}

// layer 3: Y = leaky(dinv*(agg)+bias) to global (fp16), feeds pooling
__global__ __launch_bounds__(256) void agg_kernel(const __half* __restrict__ H,
                                                  const int* __restrict__ rp,
                                                  const int* __restrict__ csrc,
                                                  const float* __restrict__ dinv,
                                                  const float* __restrict__ bias,
                                                  __half* __restrict__ Y, int N) {
    int w = (blockIdx.x * blockDim.x + threadIdx.x) >> 6;
    int nA = w << 1;
    if (nA >= N) return;
    int nB = nA + 1;
    bool hasB = nB < N;
    int l = threadIdx.x & 63;
    int slot = l >> 3;
    int fo = (l & 7) << 3;
    int endA = rp[nA + 1];
    int eA = rp[nA] + slot;
    int endB = hasB ? rp[nB + 1] : 0;
    int eB = hasB ? (rp[nB] + slot) : 0;
    float a0=0,a1=0,a2=0,a3=0,a4=0,a5=0,a6=0,a7=0;
    float b0=0,b1=0,b2=0,b3=0,b4=0,b5=0,b6=0,b7=0;
    while (eA + 8 < endA && eB + 8 < endB) {
        int sA0 = csrc[eA], sA1 = csrc[eA + 8];
        int sB0 = csrc[eB], sB1 = csrc[eB + 8];
        h8 vA0 = *(const h8*)&H[(size_t)sA0 * 64 + fo];
        h8 vA1 = *(const h8*)&H[(size_t)sA1 * 64 + fo];
        h8 vB0 = *(const h8*)&H[(size_t)sB0 * 64 + fo];
        h8 vB1 = *(const h8*)&H[(size_t)sB1 * 64 + fo];
        ACC8(vA0, a0,a1,a2,a3,a4,a5,a6,a7);
        ACC8(vA1, a0,a1,a2,a3,a4,a5,a6,a7);
        ACC8(vB0, b0,b1,b2,b3,b4,b5,b6,b7);
        ACC8(vB1, b0,b1,b2,b3,b4,b5,b6,b7);
        eA += 16; eB += 16;
    }
    while (eA + 8 < endA) {
        int s0 = csrc[eA], s1 = csrc[eA + 8];
        h8 v0 = *(const h8*)&H[(size_t)s0 * 64 + fo];
        h8 v1 = *(const h8*)&H[(size_t)s1 * 64 + fo];
        ACC8(v0, a0,a1,a2,a3,a4,a5,a6,a7);
        ACC8(v1, a0,a1,a2,a3,a4,a5,a6,a7);
        eA += 16;
    }
    while (eB + 8 < endB) {
        int s0 = csrc[eB], s1 = csrc[eB + 8];
        h8 v0 = *(const h8*)&H[(size_t)s0 * 64 + fo];
        h8 v1 = *(const h8*)&H[(size_t)s1 * 64 + fo];
        ACC8(v0, b0,b1,b2,b3,b4,b5,b6,b7);
        ACC8(v1, b0,b1,b2,b3,b4,b5,b6,b7);
        eB += 16;
    }
    if (eA < endA) {
        h8 v0 = *(const h8*)&H[(size_t)csrc[eA] * 64 + fo];
        ACC8(v0, a0,a1,a2,a3,a4,a5,a6,a7);
    }
    if (eB < endB) {
        h8 v0 = *(const h8*)&H[(size_t)csrc[eB] * 64 + fo];
        ACC8(v0, b0,b1,b2,b3,b4,b5,b6,b7);
    }
    #pragma unroll
    for (int m = 8; m <= 32; m <<= 1) {
        a0 += __shfl_xor(a0, m); a1 += __shfl_xor(a1, m);
        a2 += __shfl_xor(a2, m); a3 += __shfl_xor(a3, m);
        a4 += __shfl_xor(a4, m); a5 += __shfl_xor(a5, m);
        a6 += __shfl_xor(a6, m); a7 += __shfl_xor(a7, m);
        b0 += __shfl_xor(b0, m); b1 += __shfl_xor(b1, m);
        b2 += __shfl_xor(b2, m); b3 += __shfl_xor(b3, m);
        b4 += __shfl_xor(b4, m); b5 += __shfl_xor(b5, m);
        b6 += __shfl_xor(b6, m); b7 += __shfl_xor(b7, m);
    }
    if (l < 8) {
        float4 bv0 = *(const float4*)&bias[fo];
        float4 bv1 = *(const float4*)&bias[fo + 4];
        {
            h8 hs = *(const h8*)&H[(size_t)nA * 64 + fo];
            float2 s0 = __half22float2(hs.a), s1 = __half22float2(hs.b);
            float2 s2 = __half22float2(hs.c), s3 = __half22float2(hs.d);
            float dv = dinv[nA];
            float o0 = LRELU(dv * (a0 + s0.x) + bv0.x);
            float o1 = LRELU(dv * (a1 + s0.y) + bv0.y);
            float o2 = LRELU(dv * (a2 + s1.x) + bv0.z);
            float o3 = LRELU(dv * (a3 + s1.y) + bv0.w);
            float o4 = LRELU(dv * (a4 + s2.x) + bv1.x);
            float o5 = LRELU(dv * (a5 + s2.y) + bv1.y);
            float o6 = LRELU(dv * (a6 + s3.x) + bv1.z);
            float o7 = LRELU(dv * (a7 + s3.y) + bv1.w);
            h8 o;
            o.a = __floats2half2_rn(o0, o1);
            o.b = __floats2half2_rn(o2, o3);
            o.c = __floats2half2_rn(o4, o5);
            o.d = __floats2half2_rn(o6, o7);
            *(h8*)&Y[(size_t)nA * 64 + fo] = o;
        }
        if (hasB) {
            h8 hs = *(const h8*)&H[(size_t)nB * 64 + fo];
            float2 s0 = __half22float2(hs.a), s1 = __half22float2(hs.b);
            float2 s2 = __half22float2(hs.c), s3 = __half22float2(hs.d);
            float dv = dinv[nB];
            float o0 = LRELU(dv * (b0 + s0.x) + bv0.x);
            float o1 = LRELU(dv * (b1 + s0.y) + bv0.y);
            float o2 = LRELU(dv * (b2 + s1.x) + bv0.z);
            float o3 = LRELU(dv * (b3 + s1.y) + bv0.w);
            float o4 = LRELU(dv * (b4 + s2.x) + bv1.x);
            float o5 = LRELU(dv * (b5 + s2.y) + bv1.y);
            float o6 = LRELU(dv * (b6 + s3.x) + bv1.z);
            float o7 = LRELU(dv * (b7 + s3.y) + bv1.w);
            h8 o;
            o.a = __floats2half2_rn(o0, o1);
            o.b = __floats2half2_rn(o2, o3);
            o.c = __floats2half2_rn(o4, o5);
            o.d = __floats2half2_rn(o6, o7);
            *(h8*)&Y[(size_t)nB * 64 + fo] = o;
        }
    }
}

// ---------------- pooling + MLP ----------------

__global__ __launch_bounds__(256) void pool1_kernel(const __half* __restrict__ Y,
                                                    const int* __restrict__ gstart,
                                                    float* __restrict__ pbuf) {
    __shared__ float ssum[8][64];
    __shared__ float smax[8][64];
    int g = blockIdx.x / PARTS;
    int p = blockIdx.x % PARTS;
    int t = threadIdx.x;
    int f2 = (t & 31) * 2;
    int rg = t >> 5;
    int s = gstart[g], epos = gstart[g + 1];
    int len = epos - s;
    int lo = s + (int)((long long)len * p / PARTS);
    int hi = s + (int)((long long)len * (p + 1) / PARTS);
    float sx = 0.f, sy = 0.f, mx = -3.0e38f, my = -3.0e38f;
    for (int r = lo + rg; r < hi; r += 8) {
        __half2 v = *(const __half2*)&Y[(size_t)r * 64 + f2];
        float2 f = __half22float2(v);
        sx += f.x; sy += f.y;
        mx = fmaxf(mx, f.x); my = fmaxf(my, f.y);
    }
    ssum[rg][f2] = sx; ssum[rg][f2 + 1] = sy;
    smax[rg][f2] = mx; smax[rg][f2 + 1] = my;
    __syncthreads();
    if (t < 64) {
        float ts = 0.f, tm = -3.0e38f;
        #pragma unroll
        for (int r = 0; r < 8; ++r) {
            ts += ssum[r][t];
            tm = fmaxf(tm, smax[r][t]);
        }
        float* row = &pbuf[(size_t)(g * PARTS + p) * 128];
        row[t] = ts;
        row[64 + t] = tm;
    }
}

__global__ __launch_bounds__(256) void mlp_kernel(const float* __restrict__ pbuf,
                                                  const int* __restrict__ gstart,
                                                  const float* __restrict__ gfeat,
                                                  const float* __restrict__ w1,
                                                  const float* __restrict__ b1,
                                                  const float* __restrict__ w2,
                                                  const float* __restrict__ b2,
                                                  const float* __restrict__ w3,
                                                  const float* __restrict__ b3,
                                                  float* __restrict__ out, int NG) {
    __shared__ float hl[160];
    __shared__ float h1[256];
    __shared__ float red[128];
    int g = blockIdx.x, t = threadIdx.x;
    if (t < 64) {
        const float* base = &pbuf[(size_t)g * PARTS * 128];
        float ts = 0.f, tm = -3.0e38f;
        #pragma unroll
        for (int p = 0; p < PARTS; ++p) {
            ts += base[p * 128 + t];
            tm = fmaxf(tm, base[p * 128 + 64 + t]);
        }
        float cnt = (float)(gstart[g + 1] - gstart[g]);
        hl[t] = ts / cnt;
        hl[64 + t] = tm;
    } else if (t >= 128 && t < 160) {
        hl[t] = gfeat[g * 32 + (t - 128)];
    }
    __syncthreads();
    float a1 = b1[t];
    for (int k = 0; k < 160; ++k) a1 += hl[k] * w1[k * 256 + t];
    h1[t] = LRELU(a1);
    __syncthreads();
    if (t < 128) {
        float a2 = b2[t];
        for (int k = 0; k < 256; ++k) a2 += h1[k] * w2[k * 128 + t];
        red[t] = LRELU(a2) * w3[t];
    }
    __syncthreads();
    if (t == 0) {
        float a3 = b3[0];
        for (int k = 0; k < 128; ++k) a3 += red[k];
        out[g] = a3;
    }
}

// ---------------- launch ----------------

extern "C" void kernel_launch(void* const* d_in, const int* in_sizes, int n_in,
                              void* d_out, int out_size, void* d_ws, size_t ws_size,
                              hipStream_t stream) {
    const float* x      = (const float*)d_in[0];
    const float* gfeat  = (const float*)d_in[1];
    const float* cw1    = (const float*)d_in[2];
    const float* cb1    = (const float*)d_in[3];
    const float* cw2    = (const float*)d_in[4];
    const float* cb2    = (const float*)d_in[5];
    const float* cw3    = (const float*)d_in[6];
    const float* cb3    = (const float*)d_in[7];
    const float* fw1    = (const float*)d_in[8];
    const float* fb1    = (const float*)d_in[9];
    const float* fw2    = (const float*)d_in[10];
    const float* fb2    = (const float*)d_in[11];
    const float* ow     = (const float*)d_in[12];
    const float* ob     = (const float*)d_in[13];
    const int*   eidx   = (const int*)d_in[14];
    const int*   batch  = (const int*)d_in[15];

    const int N    = in_sizes[0] / 64;
    const int E    = in_sizes[14] / 2;
    const int NG   = in_sizes[1] / 32;
    const int NBUK = (N + 255) >> 8;          // dst buckets of 256 nodes
    const int NBLK = (E + EPB - 1) / EPB;     // sort blocks
    const int* src = eidx;
    const int* dst = eidx + E;

    // workspace carve-out (256B aligned)
    char* wp = (char*)d_ws;
    auto carve = [&](size_t bytes) {
        void* p = (void*)wp;
        wp += (bytes + 255) & ~(size_t)255;
        return p;
    };
    float*     dinv    = (float*)    carve((size_t)N * 4);
    int*       row_ptr = (int*)      carve((size_t)(N + 1) * 4);
    int*       bhist   = (int*)      carve((size_t)NBUK * NBLK * 4);
    int*       btot    = (int*)      carve((size_t)NBUK * 4);
    int*       bbase   = (int*)      carve((size_t)(NBUK + 1) * 4);
    unsigned*  bedge   = (unsigned*) carve((size_t)E * 4);
    int*       csr_src = (int*)      carve((size_t)E * 4);
    __half*    hA      = (__half*)   carve((size_t)N * 64 * 2);
    __half*    hB      = (__half*)   carve((size_t)N * 64 * 2);
    __half*    ybuf    = (__half*)   carve((size_t)N * 64 * 2);
    int*       gstart  = (int*)      carve((size_t)(NG + 1) * 4);
    float*     pbuf    = (float*)    carve((size_t)NG * PARTS * 128 * 4);
    _Float16*  Bf      = (_Float16*) carve((size_t)3 * 4096 * 2);
    float*     outf    = (float*)d_out;

    hist1_kernel<<<NBLK, 256, 0, stream>>>(dst, bhist, NBLK, E, NBUK);
    scanb_kernel<<<NBUK, 256, 0, stream>>>(bhist, btot, NBLK);
    bbase_wprep_kernel<<<7, 512, 0, stream>>>(btot, bbase, NBUK, E, cw1, cw2, cw3, Bf);
    place_kernel<<<NBLK, 256, 0, stream>>>(src, dst, bbase, bhist, bedge, NBLK, E, NBUK);
    csr_kernel<<<NBUK, 256, 0, stream>>>(bedge, bbase, row_ptr, dinv, csr_src,
                                         batch, gstart, N, E, NBUK, NG);

    const int gemmB = (N + 63) / 64;
    const int fuseB = (N + 15) / 16;           // 8 waves x 2 nodes
    const int aggB  = ((N + 1) / 2 + 3) / 4;   // 2 nodes per wave, 4 waves per block

    gemm_mfma_kernel<<<gemmB, 256, 0, stream>>>(x, Bf, dinv, hA, N);
    agg_gemm_kernel<<<fuseB, 512, 0, stream>>>(hA, row_ptr, csr_src, dinv, cb1,
                                               Bf + 4096, hB, N);
    agg_gemm_kernel<<<fuseB, 512, 0, stream>>>(hB, row_ptr, csr_src, dinv, cb2,
                                               Bf + 8192, hA, N);
    agg_kernel<<<aggB, 256, 0, stream>>>(hA, row_ptr, csr_src, dinv, cb3, ybuf, N);

    pool1_kernel<<<NG * PARTS, 256, 0, stream>>>(ybuf, gstart, pbuf);
    mlp_kernel<<<NG, 256, 0, stream>>>(pbuf, gstart, gfeat, fw1, fb1, fw2, fb2, ow, ob, outf, NG);
}